// Round 1
// baseline (167.450 us; speedup 1.0000x reference)
//
#include <hip/hip_runtime.h>

#define T_TOK 2048
#define D_DIM 512
#define F_DIM 2048
#define E_NUM 8
#define LN_EPS 1e-5f

typedef __attribute__((ext_vector_type(8))) short bf16x8;
typedef __attribute__((ext_vector_type(4))) float floatx4;

static __device__ __forceinline__ ushort f2bf(float f) {
  union { float f; unsigned int u; } v; v.f = f;
  unsigned int u = v.u;
  return (ushort)((u + 0x7fffu + ((u >> 16) & 1u)) >> 16);  // RNE
}

static __device__ __forceinline__ void gld_lds16(const void* g, void* l) {
  __builtin_amdgcn_global_load_lds(
      (const __attribute__((address_space(1))) unsigned int*)g,
      (__attribute__((address_space(3))) unsigned int*)l, 16, 0, 0);
}

// ---------------- router + LN + out-init fused ----------------
// One wave per token: lane holds 8 of the 512 features. After the butterfly
// reduce EVERY lane has the totals, so LN-apply and out-init need no broadcast.
// Writes: eid, alpha, h0 = bf16(LN(x)) in TOKEN order, out = x + alpha*b2[e].
__global__ __launch_bounds__(256) void router_kernel(
    const float* __restrict__ x, const float* __restrict__ cent,
    const float* __restrict__ ln_g, const float* __restrict__ ln_b,
    const float* __restrict__ b2,
    int* __restrict__ eid, float* __restrict__ alphav,
    ushort* __restrict__ h0, float* __restrict__ out) {
  int wave = threadIdx.x >> 6, lane = threadIdx.x & 63;
  int t = blockIdx.x * 4 + wave;
  int c0 = lane * 8;
  const float* xp = x + (size_t)t * D_DIM + c0;
  float4 x0 = *(const float4*)xp, x1 = *(const float4*)(xp + 4);
  float xv[8] = {x0.x, x0.y, x0.z, x0.w, x1.x, x1.y, x1.z, x1.w};
  float s = 0.f, s2 = 0.f, cd[E_NUM];
#pragma unroll
  for (int j = 0; j < 8; j++) { s += xv[j]; s2 += xv[j] * xv[j]; }
#pragma unroll
  for (int e = 0; e < E_NUM; e++) {
    const float* cp = cent + (size_t)e * D_DIM + c0;
    float4 cc0 = *(const float4*)cp, cc1 = *(const float4*)(cp + 4);
    float cv[8] = {cc0.x, cc0.y, cc0.z, cc0.w, cc1.x, cc1.y, cc1.z, cc1.w};
    float a = 0.f;
#pragma unroll
    for (int j = 0; j < 8; j++) a += xv[j] * cv[j];
    cd[e] = a;
  }
#pragma unroll
  for (int m = 1; m < 64; m <<= 1) {
    s  += __shfl_xor(s,  m, 64);
    s2 += __shfl_xor(s2, m, 64);
#pragma unroll
    for (int e = 0; e < E_NUM; e++) cd[e] += __shfl_xor(cd[e], m, 64);
  }
  // all lanes now hold identical totals -> identical best/mu/rs/alpha
  int best = 0;
#pragma unroll
  for (int e = 1; e < E_NUM; e++) if (cd[e] > cd[best]) best = e;  // first-max (np.argmax)
  float mu = s / (float)D_DIM;
  float var = s2 / (float)D_DIM - mu * mu;
  if (var < 0.f) var = 0.f;
  float rs = rsqrtf(var + LN_EPS);
  float al = 1.f / (1.f + expf(-cd[best]));
  if (lane == 0) { eid[t] = best; alphav[t] = al; }

  const float* gp = ln_g + (size_t)best * D_DIM + c0;
  const float* bp = ln_b + (size_t)best * D_DIM + c0;
  union { ushort u16[8]; uint4 v; } o;
#pragma unroll
  for (int j = 0; j < 8; j++)
    o.u16[j] = f2bf((xv[j] - mu) * rs * gp[j] + bp[j]);
  *(uint4*)(h0 + (size_t)t * D_DIM + c0) = o.v;

  const float* b2p = b2 + (size_t)best * D_DIM + c0;
  float4 o0, o1;
  o0.x = xv[0] + al * b2p[0]; o0.y = xv[1] + al * b2p[1];
  o0.z = xv[2] + al * b2p[2]; o0.w = xv[3] + al * b2p[3];
  o1.x = xv[4] + al * b2p[4]; o1.y = xv[5] + al * b2p[5];
  o1.z = xv[6] + al * b2p[6]; o1.w = xv[7] + al * b2p[7];
  float* op = out + (size_t)t * D_DIM + c0;
  *(float4*)op = o0;
  *(float4*)(op + 4) = o1;
}

// ---------------- prep: block 0 = permutation; blocks 1.. = weight transpose+convert ----------------
// perm's serial latency hides under 100 MB of independent weight streaming.
// W1 [E][D][F] -> W1T [E][F][D]; W2 [E][F][D] -> W2T [E][D][F]  (f32 -> bf16)
__global__ __launch_bounds__(256) void prep_kernel(
    const float* __restrict__ W1, const float* __restrict__ W2,
    ushort* __restrict__ W1T, ushort* __restrict__ W2T,
    const int* __restrict__ eid, int* __restrict__ perm,
    int* __restrict__ cnt_g, int* __restrict__ offs_g) {
  __shared__ union { ushort t[64][34]; int i[24]; } sm;
  int tid = threadIdx.x;
  int bid = blockIdx.x;
  if (bid == 0) {
    int* cnt = sm.i; int* offs = sm.i + 8; int* cur = sm.i + 16;
    if (tid < E_NUM) cnt[tid] = 0;
    __syncthreads();
    for (int t = tid; t < T_TOK; t += 256) atomicAdd(&cnt[eid[t]], 1);
    __syncthreads();
    if (tid == 0) {
      int a = 0;
      for (int e = 0; e < E_NUM; e++) { offs[e] = a; cur[e] = a; a += cnt[e]; }
    }
    __syncthreads();
    for (int t = tid; t < T_TOK; t += 256) {
      int p = atomicAdd(&cur[eid[t]], 1);
      perm[p] = t;
    }
    if (tid < E_NUM) { cnt_g[tid] = cnt[tid]; offs_g[tid] = offs[tid]; }
    return;
  }
  bid -= 1;
  const float* src; ushort* dst; int R, C, tx, ty;
  if (bid < 4096) {                       // W1: R=512 rows, C=2048 cols
    int e = bid >> 9, tile = bid & 511;
    R = D_DIM; C = F_DIM; tx = tile & 31; ty = tile >> 5;
    src = W1 + (size_t)e * R * C; dst = W1T + (size_t)e * R * C;
  } else {                                // W2: R=2048 rows, C=512 cols
    bid -= 4096;
    int e = bid >> 9, tile = bid & 511;
    R = F_DIM; C = D_DIM; tx = tile & 7; ty = tile >> 3;
    src = W2 + (size_t)e * R * C; dst = W2T + (size_t)e * R * C;
  }
  int c0 = tx * 64, r0 = ty * 32;
  int tc = (tid & 31) * 2, tr = tid >> 5;  // tr in [0,8)
#pragma unroll
  for (int rr = 0; rr < 32; rr += 8) {
    float2 v = *(const float2*)(src + (size_t)(r0 + tr + rr) * C + c0 + tc);
    sm.t[tc][tr + rr] = f2bf(v.x);
    sm.t[tc + 1][tr + rr] = f2bf(v.y);
  }
  __syncthreads();
  int wc = tid >> 4, wj = (tid & 15) * 2;
#pragma unroll
  for (int cc = 0; cc < 64; cc += 16) {
    uint v = (uint)sm.t[cc + wc][wj] | ((uint)sm.t[cc + wc][wj + 1] << 16);
    *(uint*)(dst + (size_t)(c0 + cc + wc) * R + r0 + wj) = v;
  }
}

// ---------------- grouped GEMM, m97 structure + XOR bank swizzle ----------------
// MODE 1: H = relu(A*W1 + b1) bf16; A rows gathered token-order via perm. KTOT=512, NTOT=2048.
// MODE 2: out[tok] += alpha[tok] * (A*W2 slice)  via f32 atomics. KTOT=2048, NTOT=512,
//         bx = slice*4 + nt (4 split-K slices). out pre-initialized to x + alpha*b2 by router.
template<int KTOT, int NTOT, int MODE>
__global__ __launch_bounds__(256) void moe_gemm_kernel(
    const ushort* __restrict__ A, const ushort* __restrict__ BT,
    const float* __restrict__ bias,
    const int* __restrict__ cnt, const int* __restrict__ offs,
    const int* __restrict__ perm, const float* __restrict__ alphav,
    ushort* __restrict__ Hout, float* __restrict__ out) {
  constexpr int BK = 64;
  constexpr int KITER = 8;  // MODE1: full K=512; MODE2: one 512-slice of K=2048
  int e = blockIdx.z, mt = blockIdx.y;
  int ce = cnt[e];
  if (mt * 128 >= ce) return;  // uniform early-exit before any barrier
  int bx = blockIdx.x;
  int nt = (MODE == 1) ? bx : (bx & 3);
  int k_base = (MODE == 1) ? 0 : (bx >> 2) * 512;
  int n0 = nt * 128;
  int rowbase = offs[e] + mt * 128;

  __shared__ ushort As[128 * 64];  // [m][64], 16B-unit cols XOR-swizzled by (m&7)
  __shared__ ushort Bs[128 * 64];  // [n][64], same swizzle

  int tid = threadIdx.x;
  int lane = tid & 63, wave = tid >> 6;
  int mw = (wave & 1) * 64, nw = (wave >> 1) * 64;  // wave's 64x64 sub-tile
  int fm = lane & 15, quad = lane >> 4;
  int fm7 = fm & 7;

  // staging: round r covers rows [r*32, r*32+32); thread -> row tid>>3,
  // global col8 = (tid&7) ^ (row&7)  (so LDS slot (tid&7) holds swizzled data)
  int srow = tid >> 3;
  int scol = (((tid & 7) ^ (srow & 7)) * 8);
  const ushort* a_gp[4];
  const ushort* b_gp[4];
#pragma unroll
  for (int r = 0; r < 4; r++) {
    int ap = rowbase + r * 32 + srow;
    if (ap > T_TOK - 1) ap = T_TOK - 1;  // clamp; masked on store
    int arow;
    if constexpr (MODE == 1) arow = perm[ap];  // gather token row
    else arow = ap;                            // H already permuted-order
    a_gp[r] = A + (size_t)arow * KTOT + k_base + scol;
    b_gp[r] = BT + ((size_t)e * NTOT + n0 + r * 32 + srow) * KTOT + k_base + scol;
  }
  char* as_l = (char*)As + wave * 1024;  // wave-uniform LDS base (+ r*4096)
  char* bs_l = (char*)Bs + wave * 1024;

  floatx4 acc[4][4];
#pragma unroll
  for (int i = 0; i < 4; i++)
#pragma unroll
    for (int j = 0; j < 4; j++) acc[i][j] = (floatx4){0.f, 0.f, 0.f, 0.f};

  for (int ki = 0; ki < KITER; ki++) {
    int k0 = ki * BK;
#pragma unroll
    for (int r = 0; r < 4; r++) {
      gld_lds16(a_gp[r] + k0, as_l + r * 4096);
      gld_lds16(b_gp[r] + k0, bs_l + r * 4096);
    }
    __syncthreads();
#pragma unroll
    for (int ks = 0; ks < 2; ks++) {
      int c8 = ((ks * 4 + quad) ^ fm7) * 8;  // swizzled 16B-col within the 64-elem row
      bf16x8 af[4], bfr[4];
#pragma unroll
      for (int i = 0; i < 4; i++) {
        af[i]  = *(const bf16x8*)(As + (mw + i * 16 + fm) * 64 + c8);
        bfr[i] = *(const bf16x8*)(Bs + (nw + i * 16 + fm) * 64 + c8);
      }
#pragma unroll
      for (int mi = 0; mi < 4; mi++)
#pragma unroll
        for (int ni = 0; ni < 4; ni++)
          acc[mi][ni] = __builtin_amdgcn_mfma_f32_16x16x32_bf16(af[mi], bfr[ni], acc[mi][ni], 0, 0, 0);
    }
    __syncthreads();
  }

  // C/D layout: col = lane&15, row = quad*4 + reg (m89/m91 verified)
  if (MODE == 1) {
    float bv[4];
#pragma unroll
    for (int ni = 0; ni < 4; ni++) bv[ni] = bias[e * NTOT + n0 + nw + ni * 16 + fm];
#pragma unroll
    for (int mi = 0; mi < 4; mi++) {
      int lmb = mt * 128 + mw + mi * 16 + quad * 4;
#pragma unroll
      for (int r = 0; r < 4; r++) {
        int lm = lmb + r;
        if (lm >= ce) continue;
        size_t row = (size_t)(offs[e] + lm);
#pragma unroll
        for (int ni = 0; ni < 4; ni++) {
          float v = acc[mi][ni][r] + bv[ni];
          v = v > 0.f ? v : 0.f;
          Hout[row * NTOT + n0 + nw + ni * 16 + fm] = f2bf(v);
        }
      }
    }
  } else {
#pragma unroll
    for (int mi = 0; mi < 4; mi++) {
      int lmb = mt * 128 + mw + mi * 16 + quad * 4;
#pragma unroll
      for (int r = 0; r < 4; r++) {
        int lm = lmb + r;
        if (lm >= ce) continue;
        int row = offs[e] + lm;
        int tok = perm[row];
        float al = alphav[tok];
        float* op = out + (size_t)tok * NTOT + n0 + nw + fm;
#pragma unroll
        for (int ni = 0; ni < 4; ni++)
          atomicAdd(op + ni * 16, al * acc[mi][ni][r]);
      }
    }
  }
}

extern "C" void kernel_launch(void* const* d_in, const int* in_sizes, int n_in,
                              void* d_out, int out_size, void* d_ws, size_t ws_size,
                              hipStream_t stream) {
  const float* x    = (const float*)d_in[0];
  const float* cent = (const float*)d_in[1];
  const float* ln_g = (const float*)d_in[2];
  const float* ln_b = (const float*)d_in[3];
  const float* W1   = (const float*)d_in[4];
  const float* b1   = (const float*)d_in[5];
  const float* W2   = (const float*)d_in[6];
  const float* b2   = (const float*)d_in[7];
  float* out = (float*)d_out;

  char* ws = (char*)d_ws;
  size_t off = 0;
  auto alloc = [&](size_t bytes) {
    char* p = ws + off;
    off += (bytes + 255) & ~(size_t)255;
    return p;
  };
  int*   eid    = (int*)alloc(T_TOK * 4);
  float* alphav = (float*)alloc(T_TOK * 4);
  int*   perm   = (int*)alloc(T_TOK * 4);
  int*   cnt    = (int*)alloc(E_NUM * 4);
  int*   offs   = (int*)alloc(E_NUM * 4);
  ushort* h0p   = (ushort*)alloc((size_t)T_TOK * D_DIM * 2);           // 2 MB bf16 (token order)
  ushort* H     = (ushort*)alloc((size_t)T_TOK * F_DIM * 2);           // 8 MB bf16 (permuted order)
  ushort* W1T   = (ushort*)alloc((size_t)E_NUM * F_DIM * D_DIM * 2);   // 16.8 MB bf16 [E][F][D]
  ushort* W2T   = (ushort*)alloc((size_t)E_NUM * D_DIM * F_DIM * 2);   // 16.8 MB bf16 [E][D][F]

  // 1) router + LN + out-init (out = x + alpha*b2[e])
  hipLaunchKernelGGL(router_kernel, dim3(T_TOK / 4), dim3(256), 0, stream,
                     x, cent, ln_g, ln_b, b2, eid, alphav, h0p, out);
  // 2) perm (block 0) overlapped with both weight transposes (blocks 1..8192)
  hipLaunchKernelGGL(prep_kernel, dim3(1 + 2 * E_NUM * 512), dim3(256), 0, stream,
                     W1, W2, W1T, W2T, eid, perm, cnt, offs);
  // 3) H = relu(LN(x)[perm] @ W1 + b1)
  hipLaunchKernelGGL((moe_gemm_kernel<D_DIM, F_DIM, 1>), dim3(F_DIM / 128, T_TOK / 128, E_NUM), dim3(256), 0, stream,
                     h0p, W1T, b1, cnt, offs, perm, alphav, H, nullptr);
  // 4) out[tok] += alpha * (H @ W2 slice), 4 split-K slices via atomics
  hipLaunchKernelGGL((moe_gemm_kernel<F_DIM, D_DIM, 2>), dim3(4 * 4, T_TOK / 128, E_NUM), dim3(256), 0, stream,
                     H, W2T, nullptr, cnt, offs, perm, alphav, nullptr, out);
}

// Round 2
// 161.871 us; speedup vs baseline: 1.0345x; 1.0345x over previous
//
#include <hip/hip_runtime.h>

#define T_TOK 2048
#define D_DIM 512
#define F_DIM 2048
#define E_NUM 8
#define LN_EPS 1e-5f

typedef __attribute__((ext_vector_type(8))) short bf16x8;
typedef __attribute__((ext_vector_type(4))) float floatx4;

static __device__ __forceinline__ ushort f2bf(float f) {
  union { float f; unsigned int u; } v; v.f = f;
  unsigned int u = v.u;
  return (ushort)((u + 0x7fffu + ((u >> 16) & 1u)) >> 16);  // RNE
}

static __device__ __forceinline__ void gld_lds16(const void* g, void* l) {
  __builtin_amdgcn_global_load_lds(
      (const __attribute__((address_space(1))) unsigned int*)g,
      (__attribute__((address_space(3))) unsigned int*)l, 16, 0, 0);
}

// ---------------- router + LN + out-init fused ----------------
__global__ __launch_bounds__(256) void router_kernel(
    const float* __restrict__ x, const float* __restrict__ cent,
    const float* __restrict__ ln_g, const float* __restrict__ ln_b,
    const float* __restrict__ b2,
    int* __restrict__ eid, float* __restrict__ alphav,
    ushort* __restrict__ h0, float* __restrict__ out) {
  int wave = threadIdx.x >> 6, lane = threadIdx.x & 63;
  int t = blockIdx.x * 4 + wave;
  int c0 = lane * 8;
  const float* xp = x + (size_t)t * D_DIM + c0;
  float4 x0 = *(const float4*)xp, x1 = *(const float4*)(xp + 4);
  float xv[8] = {x0.x, x0.y, x0.z, x0.w, x1.x, x1.y, x1.z, x1.w};
  float s = 0.f, s2 = 0.f, cd[E_NUM];
#pragma unroll
  for (int j = 0; j < 8; j++) { s += xv[j]; s2 += xv[j] * xv[j]; }
#pragma unroll
  for (int e = 0; e < E_NUM; e++) {
    const float* cp = cent + (size_t)e * D_DIM + c0;
    float4 cc0 = *(const float4*)cp, cc1 = *(const float4*)(cp + 4);
    float cv[8] = {cc0.x, cc0.y, cc0.z, cc0.w, cc1.x, cc1.y, cc1.z, cc1.w};
    float a = 0.f;
#pragma unroll
    for (int j = 0; j < 8; j++) a += xv[j] * cv[j];
    cd[e] = a;
  }
#pragma unroll
  for (int m = 1; m < 64; m <<= 1) {
    s  += __shfl_xor(s,  m, 64);
    s2 += __shfl_xor(s2, m, 64);
#pragma unroll
    for (int e = 0; e < E_NUM; e++) cd[e] += __shfl_xor(cd[e], m, 64);
  }
  int best = 0;
#pragma unroll
  for (int e = 1; e < E_NUM; e++) if (cd[e] > cd[best]) best = e;  // first-max (np.argmax)
  float mu = s / (float)D_DIM;
  float var = s2 / (float)D_DIM - mu * mu;
  if (var < 0.f) var = 0.f;
  float rs = rsqrtf(var + LN_EPS);
  float al = 1.f / (1.f + expf(-cd[best]));
  if (lane == 0) { eid[t] = best; alphav[t] = al; }

  const float* gp = ln_g + (size_t)best * D_DIM + c0;
  const float* bp = ln_b + (size_t)best * D_DIM + c0;
  union { ushort u16[8]; uint4 v; } o;
#pragma unroll
  for (int j = 0; j < 8; j++)
    o.u16[j] = f2bf((xv[j] - mu) * rs * gp[j] + bp[j]);
  *(uint4*)(h0 + (size_t)t * D_DIM + c0) = o.v;

  const float* b2p = b2 + (size_t)best * D_DIM + c0;
  float4 o0, o1;
  o0.x = xv[0] + al * b2p[0]; o0.y = xv[1] + al * b2p[1];
  o0.z = xv[2] + al * b2p[2]; o0.w = xv[3] + al * b2p[3];
  o1.x = xv[4] + al * b2p[4]; o1.y = xv[5] + al * b2p[5];
  o1.z = xv[6] + al * b2p[6]; o1.w = xv[7] + al * b2p[7];
  float* op = out + (size_t)t * D_DIM + c0;
  *(float4*)op = o0;
  *(float4*)(op + 4) = o1;
}

// ---------------- prep: block 0 = permutation; blocks 1.. = transpose+convert ----------------
// Widened streaming: float4 (16B) loads, uint4 (16B) stores through a 64x32 LDS tile.
// W1 [E][D][F] -> W1T [E][F][D]; W2 [E][F][D] -> W2T [E][D][F]  (f32 -> bf16)
__global__ __launch_bounds__(256) void prep_kernel(
    const float* __restrict__ W1, const float* __restrict__ W2,
    ushort* __restrict__ W1T, ushort* __restrict__ W2T,
    const int* __restrict__ eid, int* __restrict__ perm,
    int* __restrict__ cnt_g, int* __restrict__ offs_g) {
  __shared__ union { ushort t[64][34]; int i[24]; } sm;
  int tid = threadIdx.x;
  int bid = blockIdx.x;
  if (bid == 0) {
    int* cnt = sm.i; int* offs = sm.i + 8; int* cur = sm.i + 16;
    if (tid < E_NUM) cnt[tid] = 0;
    __syncthreads();
    for (int t = tid; t < T_TOK; t += 256) atomicAdd(&cnt[eid[t]], 1);
    __syncthreads();
    if (tid == 0) {
      int a = 0;
      for (int e = 0; e < E_NUM; e++) { offs[e] = a; cur[e] = a; a += cnt[e]; }
    }
    __syncthreads();
    for (int t = tid; t < T_TOK; t += 256) {
      int p = atomicAdd(&cur[eid[t]], 1);
      perm[p] = t;
    }
    if (tid < E_NUM) { cnt_g[tid] = cnt[tid]; offs_g[tid] = offs[tid]; }
    return;
  }
  bid -= 1;
  const float* src; ushort* dst; int R, C, tx, ty;
  if (bid < 4096) {                       // W1: R=512 rows, C=2048 cols
    int e = bid >> 9, tile = bid & 511;
    R = D_DIM; C = F_DIM; tx = tile & 31; ty = tile >> 5;
    src = W1 + (size_t)e * R * C; dst = W1T + (size_t)e * R * C;
  } else {                                // W2: R=2048 rows, C=512 cols
    bid -= 4096;
    int e = bid >> 9, tile = bid & 511;
    R = F_DIM; C = D_DIM; tx = tile & 7; ty = tile >> 3;
    src = W2 + (size_t)e * R * C; dst = W2T + (size_t)e * R * C;
  }
  int c0 = tx * 64, r0 = ty * 32;
  // load phase: thread -> col4 (tid&15)*4, rows tr and tr+16
  int tc = (tid & 15) * 4, tr = tid >> 4;
#pragma unroll
  for (int rr = 0; rr < 32; rr += 16) {
    float4 v = *(const float4*)(src + (size_t)(r0 + tr + rr) * C + c0 + tc);
    sm.t[tc + 0][tr + rr] = f2bf(v.x);
    sm.t[tc + 1][tr + rr] = f2bf(v.y);
    sm.t[tc + 2][tr + rr] = f2bf(v.z);
    sm.t[tc + 3][tr + rr] = f2bf(v.w);
  }
  __syncthreads();
  // store phase: thread -> col tid>>2, 8 consecutive rows (tid&3)*8; one uint4
  int wc = tid >> 2, wj = (tid & 3) * 8;
  union { ushort u[8]; uint4 v; } o;
#pragma unroll
  for (int j = 0; j < 8; j++) o.u[j] = sm.t[wc][wj + j];
  *(uint4*)(dst + (size_t)(c0 + wc) * R + r0 + wj) = o.v;
}

// ---------------- grouped GEMM: double-buffered LDS + counted vmcnt pipeline ----------------
// MODE 1: H = relu(A*W1 + b1) bf16; A rows gathered token-order via perm. KTOT=512, NTOT=2048.
// MODE 2: out[tok] += alpha[tok] * (A*W2 slice)  via f32 atomics. KTOT=2048, NTOT=512,
//         bx = slice*4 + nt. out pre-initialized to x + alpha*b2 by router.
// Pipeline: stage(k+1) issued BEFORE waiting on tile k; wait is s_waitcnt vmcnt(8)
// (8 own loads of the CURRENT tile are the oldest outstanding) + raw s_barrier.
// __syncthreads is NOT used in the K-loop (it would drain vmcnt to 0 and kill the overlap).
template<int KTOT, int NTOT, int MODE>
__global__ __launch_bounds__(256) void moe_gemm_kernel(
    const ushort* __restrict__ A, const ushort* __restrict__ BT,
    const float* __restrict__ bias,
    const int* __restrict__ cnt, const int* __restrict__ offs,
    const int* __restrict__ perm, const float* __restrict__ alphav,
    ushort* __restrict__ Hout, float* __restrict__ out) {
  constexpr int BK = 64;
  constexpr int KITER = 8;  // MODE1: full K=512; MODE2: one 512-slice of K=2048
  int e = blockIdx.z, mt = blockIdx.y;
  int ce = cnt[e];
  if (mt * 128 >= ce) return;  // uniform early-exit before any barrier
  int bx = blockIdx.x;
  int nt = (MODE == 1) ? bx : (bx & 3);
  int k_base = (MODE == 1) ? 0 : (bx >> 2) * 512;
  int n0 = nt * 128;
  int rowbase = offs[e] + mt * 128;

  // double-buffered tiles: 4 x 16KB = 64KB LDS
  __shared__ ushort As0[128 * 64], Bs0[128 * 64], As1[128 * 64], Bs1[128 * 64];

  int tid = threadIdx.x;
  int lane = tid & 63, wave = tid >> 6;
  int mw = (wave & 1) * 64, nw = (wave >> 1) * 64;  // wave's 64x64 sub-tile
  int fm = lane & 15, quad = lane >> 4;
  int fm7 = fm & 7;

  // staging: thread -> row tid>>3, global col8 = (tid&7) ^ (row&7) (XOR swizzle,
  // pre-applied on the GLOBAL address so the LDS destination stays lane-linear)
  int srow = tid >> 3;
  int scol = (((tid & 7) ^ (srow & 7)) * 8);
  const ushort* a_gp[4];
  const ushort* b_gp[4];
#pragma unroll
  for (int r = 0; r < 4; r++) {
    int ap = rowbase + r * 32 + srow;
    if (ap > T_TOK - 1) ap = T_TOK - 1;  // clamp; masked on store
    int arow;
    if constexpr (MODE == 1) arow = perm[ap];  // gather token row
    else arow = ap;                            // H already permuted-order
    a_gp[r] = A + (size_t)arow * KTOT + k_base + scol;
    b_gp[r] = BT + ((size_t)e * NTOT + n0 + r * 32 + srow) * KTOT + k_base + scol;
  }

  floatx4 acc[4][4];
#pragma unroll
  for (int i = 0; i < 4; i++)
#pragma unroll
    for (int j = 0; j < 4; j++) acc[i][j] = (floatx4){0.f, 0.f, 0.f, 0.f};

  auto stage = [&](int ki, ushort* Ad, ushort* Bd) {
    int k0 = ki * BK;
    char* al = (char*)Ad + wave * 1024;  // wave-uniform LDS base (+ r*4096)
    char* bl = (char*)Bd + wave * 1024;
#pragma unroll
    for (int r = 0; r < 4; r++) {
      gld_lds16(a_gp[r] + k0, al + r * 4096);
      gld_lds16(b_gp[r] + k0, bl + r * 4096);
    }
  };
  auto compute = [&](const ushort* Ac, const ushort* Bc) {
#pragma unroll
    for (int ks = 0; ks < 2; ks++) {
      int c8 = ((ks * 4 + quad) ^ fm7) * 8;  // swizzled 16B-col within the 64-elem row
      bf16x8 af[4], bfr[4];
#pragma unroll
      for (int i = 0; i < 4; i++) {
        af[i]  = *(const bf16x8*)(Ac + (mw + i * 16 + fm) * 64 + c8);
        bfr[i] = *(const bf16x8*)(Bc + (nw + i * 16 + fm) * 64 + c8);
      }
#pragma unroll
      for (int mi = 0; mi < 4; mi++)
#pragma unroll
        for (int ni = 0; ni < 4; ni++)
          acc[mi][ni] = __builtin_amdgcn_mfma_f32_16x16x32_bf16(af[mi], bfr[ni], acc[mi][ni], 0, 0, 0);
    }
  };

  stage(0, As0, Bs0);
#pragma unroll
  for (int kk = 0; kk < KITER; kk += 2) {
    // ---- tile kk (buffer 0); prefetch kk+1 into buffer 1 ----
    if (kk + 1 < KITER) {
      stage(kk + 1, As1, Bs1);
      asm volatile("s_waitcnt vmcnt(8)" ::: "memory");  // own 8 oldest = tile kk
    } else {
      asm volatile("s_waitcnt vmcnt(0)" ::: "memory");
    }
    __builtin_amdgcn_s_barrier();          // all threads' tile-kk loads landed
    __builtin_amdgcn_sched_barrier(0);     // keep ds_reads below the barrier
    compute(As0, Bs0);
    __builtin_amdgcn_s_barrier();          // all reads of buf0 done before overwrite
    // ---- tile kk+1 (buffer 1); prefetch kk+2 into buffer 0 ----
    if (kk + 2 < KITER) {
      stage(kk + 2, As0, Bs0);
      asm volatile("s_waitcnt vmcnt(8)" ::: "memory");
    } else {
      asm volatile("s_waitcnt vmcnt(0)" ::: "memory");
    }
    __builtin_amdgcn_s_barrier();
    __builtin_amdgcn_sched_barrier(0);
    compute(As1, Bs1);
    __builtin_amdgcn_s_barrier();
  }

  // C/D layout: col = lane&15, row = quad*4 + reg (m89/m91 verified)
  if (MODE == 1) {
    float bv[4];
#pragma unroll
    for (int ni = 0; ni < 4; ni++) bv[ni] = bias[e * NTOT + n0 + nw + ni * 16 + fm];
#pragma unroll
    for (int mi = 0; mi < 4; mi++) {
      int lmb = mt * 128 + mw + mi * 16 + quad * 4;
#pragma unroll
      for (int r = 0; r < 4; r++) {
        int lm = lmb + r;
        if (lm >= ce) continue;
        size_t row = (size_t)(offs[e] + lm);
#pragma unroll
        for (int ni = 0; ni < 4; ni++) {
          float v = acc[mi][ni][r] + bv[ni];
          v = v > 0.f ? v : 0.f;
          Hout[row * NTOT + n0 + nw + ni * 16 + fm] = f2bf(v);
        }
      }
    }
  } else {
#pragma unroll
    for (int mi = 0; mi < 4; mi++) {
      int lmb = mt * 128 + mw + mi * 16 + quad * 4;
#pragma unroll
      for (int r = 0; r < 4; r++) {
        int lm = lmb + r;
        if (lm >= ce) continue;
        int row = offs[e] + lm;
        int tok = perm[row];
        float al = alphav[tok];
        float* op = out + (size_t)tok * NTOT + n0 + nw + fm;
#pragma unroll
        for (int ni = 0; ni < 4; ni++)
          atomicAdd(op + ni * 16, al * acc[mi][ni][r]);
      }
    }
  }
}

extern "C" void kernel_launch(void* const* d_in, const int* in_sizes, int n_in,
                              void* d_out, int out_size, void* d_ws, size_t ws_size,
                              hipStream_t stream) {
  const float* x    = (const float*)d_in[0];
  const float* cent = (const float*)d_in[1];
  const float* ln_g = (const float*)d_in[2];
  const float* ln_b = (const float*)d_in[3];
  const float* W1   = (const float*)d_in[4];
  const float* b1   = (const float*)d_in[5];
  const float* W2   = (const float*)d_in[6];
  const float* b2   = (const float*)d_in[7];
  float* out = (float*)d_out;

  char* ws = (char*)d_ws;
  size_t off = 0;
  auto alloc = [&](size_t bytes) {
    char* p = ws + off;
    off += (bytes + 255) & ~(size_t)255;
    return p;
  };
  int*   eid    = (int*)alloc(T_TOK * 4);
  float* alphav = (float*)alloc(T_TOK * 4);
  int*   perm   = (int*)alloc(T_TOK * 4);
  int*   cnt    = (int*)alloc(E_NUM * 4);
  int*   offs   = (int*)alloc(E_NUM * 4);
  ushort* h0p   = (ushort*)alloc((size_t)T_TOK * D_DIM * 2);           // 2 MB bf16 (token order)
  ushort* H     = (ushort*)alloc((size_t)T_TOK * F_DIM * 2);           // 8 MB bf16 (permuted order)
  ushort* W1T   = (ushort*)alloc((size_t)E_NUM * F_DIM * D_DIM * 2);   // 16.8 MB bf16 [E][F][D]
  ushort* W2T   = (ushort*)alloc((size_t)E_NUM * D_DIM * F_DIM * 2);   // 16.8 MB bf16 [E][D][F]

  // 1) router + LN + out-init (out = x + alpha*b2[e])
  hipLaunchKernelGGL(router_kernel, dim3(T_TOK / 4), dim3(256), 0, stream,
                     x, cent, ln_g, ln_b, b2, eid, alphav, h0p, out);
  // 2) perm (block 0) overlapped with both weight transposes (blocks 1..8192)
  hipLaunchKernelGGL(prep_kernel, dim3(1 + 2 * E_NUM * 512), dim3(256), 0, stream,
                     W1, W2, W1T, W2T, eid, perm, cnt, offs);
  // 3) H = relu(LN(x)[perm] @ W1 + b1)
  hipLaunchKernelGGL((moe_gemm_kernel<D_DIM, F_DIM, 1>), dim3(F_DIM / 128, T_TOK / 128, E_NUM), dim3(256), 0, stream,
                     h0p, W1T, b1, cnt, offs, perm, alphav, H, nullptr);
  // 4) out[tok] += alpha * (H @ W2 slice), 4 split-K slices via atomics
  hipLaunchKernelGGL((moe_gemm_kernel<F_DIM, D_DIM, 2>), dim3(4 * 4, T_TOK / 128, E_NUM), dim3(256), 0, stream,
                     H, W2T, nullptr, cnt, offs, perm, alphav, nullptr, out);
}

// Round 3
// 159.201 us; speedup vs baseline: 1.0518x; 1.0168x over previous
//
#include <hip/hip_runtime.h>

#define T_TOK 2048
#define D_DIM 512
#define F_DIM 2048
#define E_NUM 8
#define LN_EPS 1e-5f

typedef __attribute__((ext_vector_type(8))) short bf16x8;
typedef __attribute__((ext_vector_type(4))) float floatx4;

static __device__ __forceinline__ ushort f2bf(float f) {
  union { float f; unsigned int u; } v; v.f = f;
  unsigned int u = v.u;
  return (ushort)((u + 0x7fffu + ((u >> 16) & 1u)) >> 16);  // RNE
}

static __device__ __forceinline__ uint cvt_pk_bf16(float lo, float hi) {
  uint r;  // dst = bf16(lo) | bf16(hi)<<16, RNE
  asm("v_cvt_pk_bf16_f32 %0, %1, %2" : "=v"(r) : "v"(lo), "v"(hi));
  return r;
}

static __device__ __forceinline__ float f4c(const float4& v, int i) {
  return i == 0 ? v.x : i == 1 ? v.y : i == 2 ? v.z : v.w;
}

static __device__ __forceinline__ void gld_lds16(const void* g, void* l) {
  __builtin_amdgcn_global_load_lds(
      (const __attribute__((address_space(1))) unsigned int*)g,
      (__attribute__((address_space(3))) unsigned int*)l, 16, 0, 0);
}

// ---------------- router + LN + out-init fused ----------------
__global__ __launch_bounds__(256) void router_kernel(
    const float* __restrict__ x, const float* __restrict__ cent,
    const float* __restrict__ ln_g, const float* __restrict__ ln_b,
    const float* __restrict__ b2,
    int* __restrict__ eid, float* __restrict__ alphav,
    ushort* __restrict__ h0, float* __restrict__ out) {
  int wave = threadIdx.x >> 6, lane = threadIdx.x & 63;
  int t = blockIdx.x * 4 + wave;
  int c0 = lane * 8;
  const float* xp = x + (size_t)t * D_DIM + c0;
  float4 x0 = *(const float4*)xp, x1 = *(const float4*)(xp + 4);
  float xv[8] = {x0.x, x0.y, x0.z, x0.w, x1.x, x1.y, x1.z, x1.w};
  float s = 0.f, s2 = 0.f, cd[E_NUM];
#pragma unroll
  for (int j = 0; j < 8; j++) { s += xv[j]; s2 += xv[j] * xv[j]; }
#pragma unroll
  for (int e = 0; e < E_NUM; e++) {
    const float* cp = cent + (size_t)e * D_DIM + c0;
    float4 cc0 = *(const float4*)cp, cc1 = *(const float4*)(cp + 4);
    float cv[8] = {cc0.x, cc0.y, cc0.z, cc0.w, cc1.x, cc1.y, cc1.z, cc1.w};
    float a = 0.f;
#pragma unroll
    for (int j = 0; j < 8; j++) a += xv[j] * cv[j];
    cd[e] = a;
  }
#pragma unroll
  for (int m = 1; m < 64; m <<= 1) {
    s  += __shfl_xor(s,  m, 64);
    s2 += __shfl_xor(s2, m, 64);
#pragma unroll
    for (int e = 0; e < E_NUM; e++) cd[e] += __shfl_xor(cd[e], m, 64);
  }
  int best = 0;
#pragma unroll
  for (int e = 1; e < E_NUM; e++) if (cd[e] > cd[best]) best = e;  // first-max (np.argmax)
  float mu = s / (float)D_DIM;
  float var = s2 / (float)D_DIM - mu * mu;
  if (var < 0.f) var = 0.f;
  float rs = rsqrtf(var + LN_EPS);
  float al = 1.f / (1.f + expf(-cd[best]));
  if (lane == 0) { eid[t] = best; alphav[t] = al; }

  const float* gp = ln_g + (size_t)best * D_DIM + c0;
  const float* bp = ln_b + (size_t)best * D_DIM + c0;
  union { ushort u16[8]; uint4 v; } o;
#pragma unroll
  for (int j = 0; j < 8; j++)
    o.u16[j] = f2bf((xv[j] - mu) * rs * gp[j] + bp[j]);
  *(uint4*)(h0 + (size_t)t * D_DIM + c0) = o.v;

  const float* b2p = b2 + (size_t)best * D_DIM + c0;
  float4 o0, o1;
  o0.x = xv[0] + al * b2p[0]; o0.y = xv[1] + al * b2p[1];
  o0.z = xv[2] + al * b2p[2]; o0.w = xv[3] + al * b2p[3];
  o1.x = xv[4] + al * b2p[4]; o1.y = xv[5] + al * b2p[5];
  o1.z = xv[6] + al * b2p[6]; o1.w = xv[7] + al * b2p[7];
  float* op = out + (size_t)t * D_DIM + c0;
  *(float4*)op = o0;
  *(float4*)(op + 4) = o1;
}

// ---------------- permutation (tiny, 1 block) ----------------
__global__ __launch_bounds__(1024) void perm_kernel(
    const int* __restrict__ eid, int* __restrict__ perm,
    int* __restrict__ cnt_g, int* __restrict__ offs_g) {
  __shared__ int cnt[E_NUM], offs[E_NUM], cur[E_NUM];
  if (threadIdx.x < E_NUM) cnt[threadIdx.x] = 0;
  __syncthreads();
  for (int t = threadIdx.x; t < T_TOK; t += 1024) atomicAdd(&cnt[eid[t]], 1);
  __syncthreads();
  if (threadIdx.x == 0) {
    int a = 0;
    for (int e = 0; e < E_NUM; e++) { offs[e] = a; cur[e] = a; a += cnt[e]; }
  }
  __syncthreads();
  for (int t = threadIdx.x; t < T_TOK; t += 1024) {
    int p = atomicAdd(&cur[eid[t]], 1);
    perm[p] = t;
  }
  if (threadIdx.x < E_NUM) { cnt_g[threadIdx.x] = cnt[threadIdx.x]; offs_g[threadIdx.x] = offs[threadIdx.x]; }
}

// ---------------- grouped GEMM: B staged DIRECTLY from f32 weights ----------------
// B-tile (128n x 64k) loaded f32 k-major (coalesced), cvt_pk -> bf16, transposed into
// LDS Bs[n][k] via ds_write_b64. Swizzle for Bs: slot = (k>>3) ^ (n&7) ^ ((n>>3)&7)
// (extra (n>>3) bit spreads transposing writes over all 8 slots -> ~4-way writes,
//  balanced reads). As keeps the old single-XOR swizzle + global_load_lds path.
// Pipeline: A triple-buffered (gld_lds), B single LDS buffer (regs hold next tile);
// per-tile loads = 4 gld_lds + 8 dwordx4 = 12 -> steady-state wait = vmcnt(12).
// MODE 1: H = relu(A*W1 + b1), A = h0 gathered via perm. KTOT=512, NTOT=2048.
// MODE 2: out[tok] += alpha*(A*W2 slice) via f32 atomics. KTOT=2048, NTOT=512.
template<int KTOT, int NTOT, int MODE>
__global__ __launch_bounds__(256) void moe_gemm_kernel(
    const ushort* __restrict__ A, const float* __restrict__ W,
    const float* __restrict__ bias,
    const int* __restrict__ cnt, const int* __restrict__ offs,
    const int* __restrict__ perm, const float* __restrict__ alphav,
    ushort* __restrict__ Hout, float* __restrict__ out) {
  constexpr int KITER = 8;  // 8 x BK=64 = 512 K per launch-slice
  int gid = blockIdx.x;
  int e, mt, nt, k_base;
  if (MODE == 1) {
    // group the ~2 mt-blocks of one (e,nt) W-panel onto one XCD (gid%8 const in mt)
    int w = (gid & 7) | ((gid >> 7) << 3);   // 0..127 = e*16+nt
    mt = (gid >> 3) & 15;
    nt = w & 15; e = w >> 4; k_base = 0;
  } else {
    // group the 4 nt-blocks of one (e,mt,slice) A-slice onto one XCD
    int low5 = gid & 31;
    nt = low5 >> 3;                          // 0..3
    int q = (low5 & 7) | ((gid >> 5) << 3);  // 0..511 = (e<<6)|(mt<<2)|slice
    int slice = q & 3; mt = (q >> 2) & 15; e = q >> 6;
    k_base = slice * 512;
  }
  int ce = cnt[e];
  if (mt * 128 >= ce) return;  // uniform early-exit before any barrier
  int n0 = nt * 128;
  int rowbase = offs[e] + mt * 128;

  __shared__ ushort As[3][128 * 64];  // 48 KB, triple-buffered
  __shared__ ushort Bs[128 * 64];     // 16 KB, single (regs hold next tile)

  int tid = threadIdx.x;
  int lane = tid & 63, wave = tid >> 6;
  int mw = (wave & 1) * 64, nw = (wave >> 1) * 64;  // wave's 64x64 sub-tile
  int fm = lane & 15, quad = lane >> 4;
  int fm7 = fm & 7;

  // ---- A staging setup (unchanged m97 path, pre-swizzled global col) ----
  int srow = tid >> 3;
  int scol = (((tid & 7) ^ (srow & 7)) * 8);
  const ushort* a_gp[4];
#pragma unroll
  for (int r = 0; r < 4; r++) {
    int ap = rowbase + r * 32 + srow;
    if (ap > T_TOK - 1) ap = T_TOK - 1;  // clamp; masked on store
    int arow;
    if constexpr (MODE == 1) arow = perm[ap];  // gather token row
    else arow = ap;                            // H already permuted-order
    a_gp[r] = A + (size_t)arow * KTOT + k_base + scol;
  }

  // ---- B staging setup: thread covers (k = kq2*8..+7) x (n = nq*4..+3) ----
  int nq = tid & 31, kq2 = tid >> 5;  // kq2: 0..7
  const float* w_gp = W + ((size_t)e * KTOT + k_base + kq2 * 8) * NTOT + n0 + nq * 4;
  int wr_off[4];
#pragma unroll
  for (int i = 0; i < 4; i++) {
    int n = nq * 4 + i;
    int slot = kq2 ^ (n & 7) ^ ((n >> 3) & 7);
    wr_off[i] = n * 128 + slot * 16;  // byte offset; +g*8 within slot
  }

  floatx4 acc[4][4];
#pragma unroll
  for (int i = 0; i < 4; i++)
#pragma unroll
    for (int j = 0; j < 4; j++) acc[i][j] = (floatx4){0.f, 0.f, 0.f, 0.f};

  auto stageA = [&](int ki, int buf) {
    int k0 = ki * 64;
    char* al = (char*)As[buf] + wave * 1024;
#pragma unroll
    for (int r = 0; r < 4; r++) gld_lds16(a_gp[r] + k0, al + r * 4096);
  };
  auto loadB = [&](int ki, float4* br) {
#pragma unroll
    for (int g = 0; g < 2; g++)
#pragma unroll
      for (int j = 0; j < 4; j++)
        br[g * 4 + j] = *(const float4*)(w_gp + (size_t)(ki * 64 + g * 4 + j) * NTOT);
  };
  auto writeB = [&](const float4* br) {
#pragma unroll
    for (int g = 0; g < 2; g++)
#pragma unroll
      for (int i = 0; i < 4; i++) {
        uint w0 = cvt_pk_bf16(f4c(br[g * 4 + 0], i), f4c(br[g * 4 + 1], i));
        uint w1 = cvt_pk_bf16(f4c(br[g * 4 + 2], i), f4c(br[g * 4 + 3], i));
        *(uint2*)((char*)Bs + wr_off[i] + g * 8) = (uint2){w0, w1};
      }
  };
  auto compute = [&](const ushort* Ac) {
#pragma unroll
    for (int ks = 0; ks < 2; ks++) {
      int c8a = ((ks * 4 + quad) ^ fm7) * 8;
      bf16x8 af[4], bfr[4];
#pragma unroll
      for (int i = 0; i < 4; i++)
        af[i] = *(const bf16x8*)(Ac + (mw + i * 16 + fm) * 64 + c8a);
#pragma unroll
      for (int i = 0; i < 4; i++) {
        int rhi = i * 2 + (fm >> 3);  // (row>>3)&7 ; nw>>3 is 0 mod 8
        int c8b = (((ks * 4 + quad) ^ fm7) ^ rhi) * 8;
        bfr[i] = *(const bf16x8*)(Bs + (nw + i * 16 + fm) * 64 + c8b);
      }
#pragma unroll
      for (int mi = 0; mi < 4; mi++)
#pragma unroll
        for (int ni = 0; ni < 4; ni++)
          acc[mi][ni] = __builtin_amdgcn_mfma_f32_16x16x32_bf16(af[mi], bfr[ni], acc[mi][ni], 0, 0, 0);
    }
  };

  float4 breg0[8], breg1[8];
  stageA(0, 0);
  loadB(0, breg0);
#pragma unroll
  for (int kt = 0; kt < KITER; kt++) {
    float4* cur = (kt & 1) ? breg1 : breg0;
    float4* nxt = (kt & 1) ? breg0 : breg1;
    if (kt + 1 < KITER) {
      stageA(kt + 1, (kt + 1) % 3);
      loadB(kt + 1, nxt);
      __builtin_amdgcn_sched_barrier(0);
      asm volatile("s_waitcnt vmcnt(12)" ::: "memory");  // tile kt (oldest 12) landed
    } else {
      __builtin_amdgcn_sched_barrier(0);
      asm volatile("s_waitcnt vmcnt(0)" ::: "memory");
    }
    __builtin_amdgcn_s_barrier();        // all waves: loads landed + done reading Bs
    writeB(cur);                         // transpose-convert into Bs
    asm volatile("s_waitcnt lgkmcnt(0)" ::: "memory");
    __builtin_amdgcn_s_barrier();        // Bs visible to all waves
    __builtin_amdgcn_sched_barrier(0);   // keep ds_reads below the barrier
    compute(As[kt % 3]);
  }

  // C/D layout: col = lane&15, row = quad*4 + reg (m89/m91 verified)
  if (MODE == 1) {
    float bv[4];
#pragma unroll
    for (int ni = 0; ni < 4; ni++) bv[ni] = bias[e * NTOT + n0 + nw + ni * 16 + fm];
#pragma unroll
    for (int mi = 0; mi < 4; mi++) {
      int lmb = mt * 128 + mw + mi * 16 + quad * 4;
#pragma unroll
      for (int r = 0; r < 4; r++) {
        int lm = lmb + r;
        if (lm >= ce) continue;
        size_t row = (size_t)(offs[e] + lm);
#pragma unroll
        for (int ni = 0; ni < 4; ni++) {
          float v = acc[mi][ni][r] + bv[ni];
          v = v > 0.f ? v : 0.f;
          Hout[row * NTOT + n0 + nw + ni * 16 + fm] = f2bf(v);
        }
      }
    }
  } else {
#pragma unroll
    for (int mi = 0; mi < 4; mi++) {
      int lmb = mt * 128 + mw + mi * 16 + quad * 4;
#pragma unroll
      for (int r = 0; r < 4; r++) {
        int lm = lmb + r;
        if (lm >= ce) continue;
        int row = offs[e] + lm;
        int tok = perm[row];
        float al = alphav[tok];
        float* op = out + (size_t)tok * NTOT + n0 + nw + fm;
#pragma unroll
        for (int ni = 0; ni < 4; ni++)
          atomicAdd(op + ni * 16, al * acc[mi][ni][r]);
      }
    }
  }
}

extern "C" void kernel_launch(void* const* d_in, const int* in_sizes, int n_in,
                              void* d_out, int out_size, void* d_ws, size_t ws_size,
                              hipStream_t stream) {
  const float* x    = (const float*)d_in[0];
  const float* cent = (const float*)d_in[1];
  const float* ln_g = (const float*)d_in[2];
  const float* ln_b = (const float*)d_in[3];
  const float* W1   = (const float*)d_in[4];
  const float* b1   = (const float*)d_in[5];
  const float* W2   = (const float*)d_in[6];
  const float* b2   = (const float*)d_in[7];
  float* out = (float*)d_out;

  char* ws = (char*)d_ws;
  size_t off = 0;
  auto alloc = [&](size_t bytes) {
    char* p = ws + off;
    off += (bytes + 255) & ~(size_t)255;
    return p;
  };
  int*   eid    = (int*)alloc(T_TOK * 4);
  float* alphav = (float*)alloc(T_TOK * 4);
  int*   perm   = (int*)alloc(T_TOK * 4);
  int*   cnt    = (int*)alloc(E_NUM * 4);
  int*   offs   = (int*)alloc(E_NUM * 4);
  ushort* h0p   = (ushort*)alloc((size_t)T_TOK * D_DIM * 2);   // 2 MB bf16 (token order)
  ushort* H     = (ushort*)alloc((size_t)T_TOK * F_DIM * 2);   // 8 MB bf16 (permuted order)

  // 1) router + LN + out-init (out = x + alpha*b2[e])
  hipLaunchKernelGGL(router_kernel, dim3(T_TOK / 4), dim3(256), 0, stream,
                     x, cent, ln_g, ln_b, b2, eid, alphav, h0p, out);
  // 2) permutation
  hipLaunchKernelGGL(perm_kernel, dim3(1), dim3(1024), 0, stream,
                     eid, perm, cnt, offs);
  // 3) H = relu(LN(x)[perm] @ W1 + b1)   (W1 consumed f32, transposed in-kernel)
  hipLaunchKernelGGL((moe_gemm_kernel<D_DIM, F_DIM, 1>), dim3(16 * 16 * E_NUM), dim3(256), 0, stream,
                     h0p, W1, b1, cnt, offs, perm, alphav, H, nullptr);
  // 4) out[tok] += alpha * (H @ W2 slice), 4 split-K slices via atomics
  hipLaunchKernelGGL((moe_gemm_kernel<F_DIM, D_DIM, 2>), dim3(4 * 4 * 16 * E_NUM), dim3(256), 0, stream,
                     H, W2, nullptr, cnt, offs, perm, alphav, nullptr, out);
}

// Round 4
// 157.120 us; speedup vs baseline: 1.0657x; 1.0132x over previous
//
#include <hip/hip_runtime.h>

#define T_TOK 2048
#define D_DIM 512
#define F_DIM 2048
#define E_NUM 8
#define LN_EPS 1e-5f

typedef __attribute__((ext_vector_type(8))) short bf16x8;
typedef __attribute__((ext_vector_type(4))) float floatx4;

static __device__ __forceinline__ ushort f2bf(float f) {
  union { float f; unsigned int u; } v; v.f = f;
  unsigned int u = v.u;
  return (ushort)((u + 0x7fffu + ((u >> 16) & 1u)) >> 16);  // RNE
}

static __device__ __forceinline__ uint cvt_pk_bf16(float lo, float hi) {
  uint r;  // dst = bf16(lo) | bf16(hi)<<16, RNE
  asm("v_cvt_pk_bf16_f32 %0, %1, %2" : "=v"(r) : "v"(lo), "v"(hi));
  return r;
}

static __device__ __forceinline__ float f4c(const float4& v, int i) {
  return i == 0 ? v.x : i == 1 ? v.y : i == 2 ? v.z : v.w;
}

static __device__ __forceinline__ void gld_lds16(const void* g, void* l) {
  __builtin_amdgcn_global_load_lds(
      (const __attribute__((address_space(1))) unsigned int*)g,
      (__attribute__((address_space(3))) unsigned int*)l, 16, 0, 0);
}

// ---------------- router + LN + out-init fused ----------------
__global__ __launch_bounds__(256) void router_kernel(
    const float* __restrict__ x, const float* __restrict__ cent,
    const float* __restrict__ ln_g, const float* __restrict__ ln_b,
    const float* __restrict__ b2,
    int* __restrict__ eid, float* __restrict__ alphav,
    ushort* __restrict__ h0, float* __restrict__ out) {
  int wave = threadIdx.x >> 6, lane = threadIdx.x & 63;
  int t = blockIdx.x * 4 + wave;
  int c0 = lane * 8;
  const float* xp = x + (size_t)t * D_DIM + c0;
  float4 x0 = *(const float4*)xp, x1 = *(const float4*)(xp + 4);
  float xv[8] = {x0.x, x0.y, x0.z, x0.w, x1.x, x1.y, x1.z, x1.w};
  float s = 0.f, s2 = 0.f, cd[E_NUM];
#pragma unroll
  for (int j = 0; j < 8; j++) { s += xv[j]; s2 += xv[j] * xv[j]; }
#pragma unroll
  for (int e = 0; e < E_NUM; e++) {
    const float* cp = cent + (size_t)e * D_DIM + c0;
    float4 cc0 = *(const float4*)cp, cc1 = *(const float4*)(cp + 4);
    float cv[8] = {cc0.x, cc0.y, cc0.z, cc0.w, cc1.x, cc1.y, cc1.z, cc1.w};
    float a = 0.f;
#pragma unroll
    for (int j = 0; j < 8; j++) a += xv[j] * cv[j];
    cd[e] = a;
  }
#pragma unroll
  for (int m = 1; m < 64; m <<= 1) {
    s  += __shfl_xor(s,  m, 64);
    s2 += __shfl_xor(s2, m, 64);
#pragma unroll
    for (int e = 0; e < E_NUM; e++) cd[e] += __shfl_xor(cd[e], m, 64);
  }
  int best = 0;
#pragma unroll
  for (int e = 1; e < E_NUM; e++) if (cd[e] > cd[best]) best = e;  // first-max (np.argmax)
  float mu = s / (float)D_DIM;
  float var = s2 / (float)D_DIM - mu * mu;
  if (var < 0.f) var = 0.f;
  float rs = rsqrtf(var + LN_EPS);
  float al = 1.f / (1.f + expf(-cd[best]));
  if (lane == 0) { eid[t] = best; alphav[t] = al; }

  const float* gp = ln_g + (size_t)best * D_DIM + c0;
  const float* bp = ln_b + (size_t)best * D_DIM + c0;
  union { ushort u16[8]; uint4 v; } o;
#pragma unroll
  for (int j = 0; j < 8; j++)
    o.u16[j] = f2bf((xv[j] - mu) * rs * gp[j] + bp[j]);
  *(uint4*)(h0 + (size_t)t * D_DIM + c0) = o.v;

  const float* b2p = b2 + (size_t)best * D_DIM + c0;
  float4 o0, o1;
  o0.x = xv[0] + al * b2p[0]; o0.y = xv[1] + al * b2p[1];
  o0.z = xv[2] + al * b2p[2]; o0.w = xv[3] + al * b2p[3];
  o1.x = xv[4] + al * b2p[4]; o1.y = xv[5] + al * b2p[5];
  o1.z = xv[6] + al * b2p[6]; o1.w = xv[7] + al * b2p[7];
  float* op = out + (size_t)t * D_DIM + c0;
  *(float4*)op = o0;
  *(float4*)(op + 4) = o1;
}

// ---------------- permutation: ballot-based, no serialized atomics ----------------
// 1024 threads (16 waves), 2 rounds of 1024 tokens. Per wave+expert: __ballot ->
// popcount rank within wave; 8-thread serial scan over the 32 (round,wave) slots.
// Order = increasing token id within expert (stable; matches argsort semantics).
__global__ __launch_bounds__(1024) void perm_kernel(
    const int* __restrict__ eid, int* __restrict__ perm,
    int* __restrict__ cnt_g, int* __restrict__ offs_g) {
  __shared__ int wcnt[32][E_NUM];
  __shared__ int wbase[32][E_NUM];
  __shared__ int cnt_s[E_NUM], offs_s[E_NUM];
  int tid = threadIdx.x, lane = tid & 63, w = tid >> 6;  // w in [0,16)
  unsigned long long below = (lane == 63) ? ~0ull >> 1 : ((1ull << lane) - 1);
  int et[2], rank[2];
#pragma unroll
  for (int rp = 0; rp < 2; rp++) {
    int t = rp * 1024 + tid;
    et[rp] = eid[t];
    rank[rp] = 0;
#pragma unroll
    for (int e = 0; e < E_NUM; e++) {
      unsigned long long m = __ballot(et[rp] == e);
      if (lane == 0) wcnt[rp * 16 + w][e] = __popcll(m);
      if (et[rp] == e) rank[rp] = __popcll(m & below);
    }
  }
  __syncthreads();
  if (tid < E_NUM) {
    int a = 0;
    for (int s = 0; s < 32; s++) { wbase[s][tid] = a; a += wcnt[s][tid]; }
    cnt_s[tid] = a;
    cnt_g[tid] = a;
  }
  __syncthreads();
  if (tid == 0) {
    int a = 0;
    for (int e = 0; e < E_NUM; e++) { offs_s[e] = a; offs_g[e] = a; a += cnt_s[e]; }
  }
  __syncthreads();
#pragma unroll
  for (int rp = 0; rp < 2; rp++) {
    int t = rp * 1024 + tid;
    int e = et[rp];
    perm[offs_s[e] + wbase[rp * 16 + w][e] + rank[rp]] = t;
  }
}

// ---------------- grouped GEMM: 64-row M-tiles for 2 blocks/CU ----------------
// Tile: 64m x 128n x 64k. 4 waves as 2m x 2n (wave-tile 32x64, acc[2][4]).
// LDS: As triple-buffer 3x8KB + Bs 16KB = 40KB -> 2 blocks/CU (latency hiding
// across blocks; the round-3 128-row version was 1 block/CU = 1 wave/SIMD with
// nothing to overlap the barrier/waitcnt stalls).
// B staged directly from f32 weights (k-major coalesced), cvt_pk -> bf16,
// transposed into swizzled Bs[n][k] (slot = k8 ^ (n&7) ^ ((n>>3)&7)).
// Grid: 1024 blocks, gid = low3 | mt<<3 | phi<<6; panel = phi*8+low3. Blocks of
// the same weight panel differ only in mt -> same gid%8 -> same XCD (L2 reuse).
// Per-tile VMEM per thread: 2 gld_lds (A) + 8 dwordx4 (B) = 10 -> steady vmcnt(10).
// MODE 1: H = relu(A*W1 + b1), A = h0 gathered via perm. KTOT=512, NTOT=2048.
// MODE 2: out[tok] += alpha*(A*W2 slice) via f32 atomics. KTOT=2048, NTOT=512.
template<int KTOT, int NTOT, int MODE>
__global__ __launch_bounds__(256) void moe_gemm_kernel(
    const ushort* __restrict__ A, const float* __restrict__ W,
    const float* __restrict__ bias,
    const int* __restrict__ cnt, const int* __restrict__ offs,
    const int* __restrict__ perm, const float* __restrict__ alphav,
    ushort* __restrict__ Hout, float* __restrict__ out) {
  constexpr int KITER = 8;  // 8 x BK=64 = 512 K per launch-slice
  int gid = blockIdx.x;
  int low3 = gid & 7, mt = (gid >> 3) & 7, phi = gid >> 6;
  int panel = phi * 8 + low3;  // 0..127
  int e, nt, k_base;
  if (MODE == 1) {
    nt = panel & 15; e = panel >> 4; k_base = 0;
  } else {
    nt = panel & 3; e = panel >> 4; k_base = ((panel >> 2) & 3) * 512;
  }
  int ce = cnt[e];
  if (mt * 64 >= ce) return;  // uniform early-exit before any barrier
  int n0 = nt * 128;
  int rowbase = offs[e] + mt * 64;

  __shared__ ushort As[3][64 * 64];  // 24 KB triple-buffered
  __shared__ ushort Bs[128 * 64];    // 16 KB single (regs hold next tile)

  int tid = threadIdx.x;
  int lane = tid & 63, wave = tid >> 6;
  int mw = (wave & 1) * 32, nw = (wave >> 1) * 64;  // wave's 32x64 sub-tile
  int fm = lane & 15, quad = lane >> 4;
  int fm7 = fm & 7;

  // ---- A staging: round r covers rows [r*32, r*32+32); thread -> row tid>>3 ----
  int srow = tid >> 3;
  int scol = (((tid & 7) ^ (srow & 7)) * 8);  // pre-swizzled global col
  const ushort* a_gp[2];
#pragma unroll
  for (int r = 0; r < 2; r++) {
    int ap = rowbase + r * 32 + srow;
    if (ap > T_TOK - 1) ap = T_TOK - 1;  // clamp; masked on store
    int arow;
    if constexpr (MODE == 1) arow = perm[ap];  // gather token row
    else arow = ap;                            // H already permuted-order
    a_gp[r] = A + (size_t)arow * KTOT + k_base + scol;
  }

  // ---- B staging: thread covers (k = kq2*8..+7) x (n = nq*4..+3) ----
  int nq = tid & 31, kq2 = tid >> 5;  // kq2: 0..7
  const float* w_gp = W + ((size_t)e * KTOT + k_base + kq2 * 8) * NTOT + n0 + nq * 4;
  int wr_off[4];
#pragma unroll
  for (int i = 0; i < 4; i++) {
    int n = nq * 4 + i;
    int slot = kq2 ^ (n & 7) ^ ((n >> 3) & 7);
    wr_off[i] = n * 128 + slot * 16;  // byte offset; +g*8 within slot
  }

  floatx4 acc[2][4];
#pragma unroll
  for (int i = 0; i < 2; i++)
#pragma unroll
    for (int j = 0; j < 4; j++) acc[i][j] = (floatx4){0.f, 0.f, 0.f, 0.f};

  auto stageA = [&](int ki, int buf) {
    int k0 = ki * 64;
    char* al = (char*)As[buf] + wave * 1024;
#pragma unroll
    for (int r = 0; r < 2; r++) gld_lds16(a_gp[r] + k0, al + r * 4096);
  };
  auto loadB = [&](int ki, float4* br) {
#pragma unroll
    for (int g = 0; g < 2; g++)
#pragma unroll
      for (int j = 0; j < 4; j++)
        br[g * 4 + j] = *(const float4*)(w_gp + (size_t)(ki * 64 + g * 4 + j) * NTOT);
  };
  auto writeB = [&](const float4* br) {
#pragma unroll
    for (int g = 0; g < 2; g++)
#pragma unroll
      for (int i = 0; i < 4; i++) {
        uint w0 = cvt_pk_bf16(f4c(br[g * 4 + 0], i), f4c(br[g * 4 + 1], i));
        uint w1 = cvt_pk_bf16(f4c(br[g * 4 + 2], i), f4c(br[g * 4 + 3], i));
        *(uint2*)((char*)Bs + wr_off[i] + g * 8) = (uint2){w0, w1};
      }
  };
  auto compute = [&](const ushort* Ac) {
#pragma unroll
    for (int ks = 0; ks < 2; ks++) {
      int c8a = ((ks * 4 + quad) ^ fm7) * 8;
      bf16x8 af[2], bfr[4];
#pragma unroll
      for (int i = 0; i < 2; i++)
        af[i] = *(const bf16x8*)(Ac + (mw + i * 16 + fm) * 64 + c8a);
#pragma unroll
      for (int i = 0; i < 4; i++) {
        int rhi = i * 2 + (fm >> 3);  // ((nw + i*16 + fm)>>3)&7 ; nw>>3 ≡ 0 mod 8
        int c8b = (((ks * 4 + quad) ^ fm7) ^ rhi) * 8;
        bfr[i] = *(const bf16x8*)(Bs + (nw + i * 16 + fm) * 64 + c8b);
      }
#pragma unroll
      for (int mi = 0; mi < 2; mi++)
#pragma unroll
        for (int ni = 0; ni < 4; ni++)
          acc[mi][ni] = __builtin_amdgcn_mfma_f32_16x16x32_bf16(af[mi], bfr[ni], acc[mi][ni], 0, 0, 0);
    }
  };

  float4 breg0[8], breg1[8];
  stageA(0, 0);
  loadB(0, breg0);
#pragma unroll
  for (int kt = 0; kt < KITER; kt++) {
    float4* cur = (kt & 1) ? breg1 : breg0;
    float4* nxt = (kt & 1) ? breg0 : breg1;
    if (kt + 1 < KITER) {
      stageA(kt + 1, (kt + 1) % 3);
      loadB(kt + 1, nxt);
      __builtin_amdgcn_sched_barrier(0);
      asm volatile("s_waitcnt vmcnt(10)" ::: "memory");  // tile kt (oldest 10) landed
    } else {
      __builtin_amdgcn_sched_barrier(0);
      asm volatile("s_waitcnt vmcnt(0)" ::: "memory");
    }
    __builtin_amdgcn_s_barrier();        // all waves: loads landed + done reading Bs
    writeB(cur);                         // transpose-convert into Bs
    asm volatile("s_waitcnt lgkmcnt(0)" ::: "memory");
    __builtin_amdgcn_s_barrier();        // Bs visible to all waves
    __builtin_amdgcn_sched_barrier(0);   // keep ds_reads below the barrier
    compute(As[kt % 3]);
  }

  // C/D layout: col = lane&15, row = quad*4 + reg (m89/m91 verified)
  if (MODE == 1) {
    float bv[4];
#pragma unroll
    for (int ni = 0; ni < 4; ni++) bv[ni] = bias[e * NTOT + n0 + nw + ni * 16 + fm];
#pragma unroll
    for (int mi = 0; mi < 2; mi++) {
      int lmb = mt * 64 + mw + mi * 16 + quad * 4;
#pragma unroll
      for (int r = 0; r < 4; r++) {
        int lm = lmb + r;
        if (lm >= ce) continue;
        size_t row = (size_t)(offs[e] + lm);
#pragma unroll
        for (int ni = 0; ni < 4; ni++) {
          float v = acc[mi][ni][r] + bv[ni];
          v = v > 0.f ? v : 0.f;
          Hout[row * NTOT + n0 + nw + ni * 16 + fm] = f2bf(v);
        }
      }
    }
  } else {
#pragma unroll
    for (int mi = 0; mi < 2; mi++) {
      int lmb = mt * 64 + mw + mi * 16 + quad * 4;
#pragma unroll
      for (int r = 0; r < 4; r++) {
        int lm = lmb + r;
        if (lm >= ce) continue;
        int row = offs[e] + lm;
        int tok = perm[row];
        float al = alphav[tok];
        float* op = out + (size_t)tok * NTOT + n0 + nw + fm;
#pragma unroll
        for (int ni = 0; ni < 4; ni++)
          atomicAdd(op + ni * 16, al * acc[mi][ni][r]);
      }
    }
  }
}

extern "C" void kernel_launch(void* const* d_in, const int* in_sizes, int n_in,
                              void* d_out, int out_size, void* d_ws, size_t ws_size,
                              hipStream_t stream) {
  const float* x    = (const float*)d_in[0];
  const float* cent = (const float*)d_in[1];
  const float* ln_g = (const float*)d_in[2];
  const float* ln_b = (const float*)d_in[3];
  const float* W1   = (const float*)d_in[4];
  const float* b1   = (const float*)d_in[5];
  const float* W2   = (const float*)d_in[6];
  const float* b2   = (const float*)d_in[7];
  float* out = (float*)d_out;

  char* ws = (char*)d_ws;
  size_t off = 0;
  auto alloc = [&](size_t bytes) {
    char* p = ws + off;
    off += (bytes + 255) & ~(size_t)255;
    return p;
  };
  int*   eid    = (int*)alloc(T_TOK * 4);
  float* alphav = (float*)alloc(T_TOK * 4);
  int*   perm   = (int*)alloc(T_TOK * 4);
  int*   cnt    = (int*)alloc(E_NUM * 4);
  int*   offs   = (int*)alloc(E_NUM * 4);
  ushort* h0p   = (ushort*)alloc((size_t)T_TOK * D_DIM * 2);   // 2 MB bf16 (token order)
  ushort* H     = (ushort*)alloc((size_t)T_TOK * F_DIM * 2);   // 8 MB bf16 (permuted order)

  // 1) router + LN + out-init (out = x + alpha*b2[e])
  hipLaunchKernelGGL(router_kernel, dim3(T_TOK / 4), dim3(256), 0, stream,
                     x, cent, ln_g, ln_b, b2, eid, alphav, h0p, out);
  // 2) permutation (ballot-based)
  hipLaunchKernelGGL(perm_kernel, dim3(1), dim3(1024), 0, stream,
                     eid, perm, cnt, offs);
  // 3) H = relu(LN(x)[perm] @ W1 + b1)   (W1 consumed f32, transposed in-kernel)
  hipLaunchKernelGGL((moe_gemm_kernel<D_DIM, F_DIM, 1>), dim3(1024), dim3(256), 0, stream,
                     h0p, W1, b1, cnt, offs, perm, alphav, H, nullptr);
  // 4) out[tok] += alpha * (H @ W2 slice), 4 split-K slices via atomics
  hipLaunchKernelGGL((moe_gemm_kernel<F_DIM, D_DIM, 2>), dim3(1024), dim3(256), 0, stream,
                     H, W2, nullptr, cnt, offs, perm, alphav, nullptr, out);
}